// Round 2
// baseline (673.017 us; speedup 1.0000x reference)
//
#include <hip/hip_runtime.h>

// Painting: sequentially alpha-composite N=128 RGBA layers onto a white canvas.
//   canvas = canvas*(1-a) + a*poly,  a = poly[:,3]*0.8 (broadcast over RGBA)
// polys: (N,1,4,H,W) fp32. Out: (1,4,H,W) fp32. Pure HBM stream (512 MiB read).
//
// R1 lesson: 256 blocks = 1 wave/SIMD -> no TLP, 810 GB/s. Fix: each step is
// affine (c -> A*c + B, A=prod(1-a) per pixel, B per channel), so split the
// layer range across the 4 waves of a block (registers), combine via LDS.
// 1024 blocks x 256 thr = 16 waves/CU, zero extra HBM traffic.

#define PH 512
#define PW 512
#define PHW (PH * PW)
#define PHW4 (PHW / 4)        // float4 groups per plane (65536)
#define OPACITY 0.8f
#define NWAVES 4              // waves per block == layer-split factor

__device__ __forceinline__ float4 f4(float v) { return make_float4(v, v, v, v); }

__global__ __launch_bounds__(256, 4) void paint_kernel(const float4* __restrict__ polys,
                                                       float4* __restrict__ out,
                                                       int n_polys) {
    __shared__ float4 sA[NWAVES][64];        // per-pixel alpha products
    __shared__ float4 sB[NWAVES][4][64];     // per-channel offsets, [ch] major for
                                             // lane-contiguous epilogue reads
    const int lane = threadIdx.x & 63;
    const int wave = threadIdx.x >> 6;
    const int gidx = blockIdx.x * 64 + lane;  // float4-group index in a plane

    // This wave's layer chunk
    const int L = n_polys / NWAVES;
    const int lstart = wave * L;
    const int lend = (wave == NWAVES - 1) ? n_polys : lstart + L;

    // Affine accumulator: x -> A*x + B  (A scalar per pixel, B per channel)
    float4 A = f4(1.f);
    float4 B0 = f4(0.f), B1 = f4(0.f), B2 = f4(0.f), B3 = f4(0.f);

    const float4* p = polys + (size_t)lstart * 4 * PHW4 + gidx;
    #pragma unroll 4
    for (int n = lstart; n < lend; ++n) {
        const float4 p0 = p[0 * PHW4];   // R plane, 1 KiB/wave, coalesced
        const float4 p1 = p[1 * PHW4];
        const float4 p2 = p[2 * PHW4];
        const float4 p3 = p[3 * PHW4];   // A plane
        p += 4 * PHW4;

        const float4 a  = make_float4(p3.x * OPACITY, p3.y * OPACITY,
                                      p3.z * OPACITY, p3.w * OPACITY);
        const float4 om = make_float4(1.f - a.x, 1.f - a.y, 1.f - a.z, 1.f - a.w);

        // A *= (1-a);  B = (1-a)*B + a*p
        A.x *= om.x; A.y *= om.y; A.z *= om.z; A.w *= om.w;
        B0.x = fmaf(a.x, p0.x, om.x * B0.x); B0.y = fmaf(a.y, p0.y, om.y * B0.y);
        B0.z = fmaf(a.z, p0.z, om.z * B0.z); B0.w = fmaf(a.w, p0.w, om.w * B0.w);
        B1.x = fmaf(a.x, p1.x, om.x * B1.x); B1.y = fmaf(a.y, p1.y, om.y * B1.y);
        B1.z = fmaf(a.z, p1.z, om.z * B1.z); B1.w = fmaf(a.w, p1.w, om.w * B1.w);
        B2.x = fmaf(a.x, p2.x, om.x * B2.x); B2.y = fmaf(a.y, p2.y, om.y * B2.y);
        B2.z = fmaf(a.z, p2.z, om.z * B2.z); B2.w = fmaf(a.w, p2.w, om.w * B2.w);
        B3.x = fmaf(a.x, p3.x, om.x * B3.x); B3.y = fmaf(a.y, p3.y, om.y * B3.y);
        B3.z = fmaf(a.z, p3.z, om.z * B3.z); B3.w = fmaf(a.w, p3.w, om.w * B3.w);
    }

    sA[wave][lane] = A;
    sB[wave][0][lane] = B0;
    sB[wave][1][lane] = B1;
    sB[wave][2][lane] = B2;
    sB[wave][3][lane] = B3;
    __syncthreads();

    // Epilogue: wave w handles channel w for all 64 groups of this block.
    // Compose chunks in layer order: c = A_w * c + B_w, starting from c = 1.
    const int ch = wave;
    float4 c = f4(1.f);
    #pragma unroll
    for (int w = 0; w < NWAVES; ++w) {
        const float4 a4 = sA[w][lane];
        const float4 b4 = sB[w][ch][lane];
        c.x = fmaf(a4.x, c.x, b4.x);
        c.y = fmaf(a4.y, c.y, b4.y);
        c.z = fmaf(a4.z, c.z, b4.z);
        c.w = fmaf(a4.w, c.w, b4.w);
    }
    out[(size_t)ch * PHW4 + gidx] = c;
}

extern "C" void kernel_launch(void* const* d_in, const int* in_sizes, int n_in,
                              void* d_out, int out_size, void* d_ws, size_t ws_size,
                              hipStream_t stream) {
    const float4* polys = (const float4*)d_in[0];
    float4* out = (float4*)d_out;
    const int n_polys = in_sizes[0] / (4 * PHW);   // 128 for the reference setup

    const int blocks = PHW4 / 64;                  // 1024 blocks, 64 groups each
    paint_kernel<<<blocks, 256, 0, stream>>>(polys, out, n_polys);
}